// Round 1
// baseline (549.076 us; speedup 1.0000x reference)
//
#include <hip/hip_runtime.h>

#define B 2
#define C 8
#define M 8
#define H 8
#define F 256
#define W 512
#define HD 32

// ---------------------------------------------------------------------------
// conv1: 3x3, C=8 -> M=8, pad (1,1). out[bm][f][w], one thread per output.
// ---------------------------------------------------------------------------
__global__ __launch_bounds__(256) void conv1_kernel(const float* __restrict__ x,
                                                    const float* __restrict__ wt,
                                                    float* __restrict__ out) {
    __shared__ float wl[72];
    int t = threadIdx.x;
    int bz = blockIdx.z;          // b*8 + m
    int b = bz >> 3, m = bz & 7;
    if (t < 72) wl[t] = wt[m * 72 + t];
    __syncthreads();
    int f = blockIdx.y;
    int w = blockIdx.x * 256 + t;
    const float* xb = x + (size_t)b * C * F * W;
    float acc = 0.f;
    for (int i = 0; i < 8; ++i) {
        const float* xi = xb + (size_t)i * F * W;
        #pragma unroll
        for (int df = 0; df < 3; ++df) {
            int ff = f + df - 1;
            if (ff < 0 || ff >= F) continue;           // wave-uniform (f uniform per block)
            const float* xr = xi + (size_t)ff * W;
            float v0 = (w - 1 >= 0) ? xr[w - 1] : 0.f;
            float v1 = xr[w];
            float v2 = (w + 1 < W) ? xr[w + 1] : 0.f;
            const float* wr = &wl[(i * 3 + df) * 3];
            acc += v0 * wr[0] + v1 * wr[1] + v2 * wr[2];
        }
    }
    out[((size_t)bz * F + f) * W + w] = acc;
}

// ---------------------------------------------------------------------------
// lin: per (b,m): out[g][w] = sum_f wt[m][g][f] * in[bm][f][w]
// 64x64 tile, BK=16, 4x4 micro-tile, float4 LDS reads.
// ---------------------------------------------------------------------------
__global__ __launch_bounds__(256) void lin_kernel(const float* __restrict__ in,
                                                  const float* __restrict__ wt,
                                                  float* __restrict__ out) {
    __shared__ float As[16][68];   // As[kk][gg] = wt[g0+gg][f0+kk]
    __shared__ float Bs[16][68];   // Bs[kk][ww] = in[f0+kk][w0+ww]
    int t = threadIdx.x;
    int bm = blockIdx.z;
    int m = bm & 7;
    const float* wm = wt + (size_t)m * F * F;
    const float* ib = in + (size_t)bm * F * W;
    float* ob = out + (size_t)bm * F * W;
    int g0 = blockIdx.y * 64, w0 = blockIdx.x * 64;
    int ty = t >> 4, tx = t & 15;
    int gg = t >> 2, fq = (t & 3) * 4;
    int lkk = t >> 4, wq = (t & 15) * 4;
    float acc[4][4] = {};
    for (int f0 = 0; f0 < F; f0 += 16) {
        float4 av = *(const float4*)&wm[(size_t)(g0 + gg) * F + f0 + fq];
        float4 bv = *(const float4*)&ib[(size_t)(f0 + lkk) * W + w0 + wq];
        As[fq + 0][gg] = av.x; As[fq + 1][gg] = av.y;
        As[fq + 2][gg] = av.z; As[fq + 3][gg] = av.w;
        *(float4*)&Bs[lkk][wq] = bv;
        __syncthreads();
        #pragma unroll
        for (int kk = 0; kk < 16; ++kk) {
            float4 a4 = *(const float4*)&As[kk][ty * 4];
            float4 b4 = *(const float4*)&Bs[kk][tx * 4];
            acc[0][0] += a4.x * b4.x; acc[0][1] += a4.x * b4.y; acc[0][2] += a4.x * b4.z; acc[0][3] += a4.x * b4.w;
            acc[1][0] += a4.y * b4.x; acc[1][1] += a4.y * b4.y; acc[1][2] += a4.y * b4.z; acc[1][3] += a4.y * b4.w;
            acc[2][0] += a4.z * b4.x; acc[2][1] += a4.z * b4.y; acc[2][2] += a4.z * b4.z; acc[2][3] += a4.z * b4.w;
            acc[3][0] += a4.w * b4.x; acc[3][1] += a4.w * b4.y; acc[3][2] += a4.w * b4.z; acc[3][3] += a4.w * b4.w;
        }
        __syncthreads();
    }
    #pragma unroll
    for (int i = 0; i < 4; ++i) {
        float4 o = make_float4(acc[i][0], acc[i][1], acc[i][2], acc[i][3]);
        *(float4*)&ob[(size_t)(g0 + ty * 4 + i) * W + w0 + tx * 4] = o;
    }
}

// ---------------------------------------------------------------------------
// conv2 (1x3, M-mix) + heads transpose + optional rotary.
// Block computes tile f[f0,f0+64) x w[w0,w0+64) for one (b,o); stages in LDS
// and writes (B,M,H,W,HD) coalesced along d with rotary applied in write phase.
// ---------------------------------------------------------------------------
__global__ __launch_bounds__(256) void conv2_heads_kernel(const float* __restrict__ in,
                                                          const float* __restrict__ wt,
                                                          float* __restrict__ outp,
                                                          int do_rot) {
    __shared__ float wl[192];           // wc2[o][i][dw]
    __shared__ float Ot[64][65];        // [f-offset][w-offset]
    int t = threadIdx.x;
    int bz = blockIdx.z;                // b*8 + o
    int b = bz >> 3, o = bz & 7;
    if (t < 192) wl[t] = wt[t];
    __syncthreads();
    int f0 = blockIdx.y * 64, w0 = blockIdx.x * 64;
    const float* ib = in + (size_t)b * M * F * W;
    int ww = t & 63, fq = (t >> 6) * 16;
    int w = w0 + ww;
    for (int ff = 0; ff < 16; ++ff) {
        int f = f0 + fq + ff;
        float acc = 0.f;
        #pragma unroll
        for (int i = 0; i < 8; ++i) {
            const float* r = ib + ((size_t)i * F + f) * W + w;
            float v0 = (w - 1 >= 0) ? r[-1] : 0.f;
            float v1 = r[0];
            float v2 = (w + 1 < W) ? r[1] : 0.f;
            const float* wr = &wl[(o * 8 + i) * 3];
            acc += v0 * wr[0] + v1 * wr[1] + v2 * wr[2];
        }
        Ot[fq + ff][ww] = acc;
    }
    __syncthreads();
    // write phase: lanes run over f-offset (=> d contiguous), iterate w
    for (int k = 0; k < 16; ++k) {
        int idx = k * 256 + t;
        int ddh = idx & 63;      // f offset in tile
        int wi = idx >> 6;       // w offset in tile
        int f = f0 + ddh;
        int h = f >> 5, d = f & 31;
        float val;
        if (do_rot) {
            float e  = Ot[ddh & ~1][wi];
            float od = Ot[ddh | 1][wi];
            int jp = d >> 1;
            float invf = exp2f(-(float)jp * 0.83048202372184058f);  // 10000^(-jp/16)
            float th = (float)(w0 + wi) * invf;
            float cs = cosf(th), sn = sinf(th);
            val = (d & 1) ? (od * cs + e * sn) : (e * cs - od * sn);
        } else {
            val = Ot[ddh][wi];
        }
        outp[(((size_t)bz * H + h) * W + (w0 + wi)) * HD + d] = val;
    }
}

// ---------------------------------------------------------------------------
// Fused attention: per (bmh, 64-row block): loop 8 chunks of 64 cols.
// scores = QK^T/16 + prev  -> written to qk output exactly once.
// online softmax, PV accumulate, final A written in (B,M,F,W) layout.
// ---------------------------------------------------------------------------
__global__ __launch_bounds__(256) void attn_kernel(const float* __restrict__ qb,
                                                   const float* __restrict__ kb,
                                                   const float* __restrict__ vb,
                                                   const float* __restrict__ prev,
                                                   float* __restrict__ qk,
                                                   float* __restrict__ abuf) {
    __shared__ float QsT[32][68];   // [d][row]
    __shared__ float KsT[32][68];   // [d][col]
    __shared__ float Vs[64][36];    // [col][d]
    __shared__ float PsT[64][68];   // [col][row]  (reused as Ot[32][68] in epilogue)
    int t = threadIdx.x;
    int w0 = blockIdx.x * 64;       // q-row block
    int bmh = blockIdx.y;           // 0..127
    const float* Q = qb + (size_t)bmh * W * HD;
    const float* K = kb + (size_t)bmh * W * HD;
    const float* V = vb + (size_t)bmh * W * HD;
    const float* P0 = prev + (size_t)bmh * W * W;
    float* QK = qk + (size_t)bmh * W * W;
    int bm = bmh >> 3, h = bmh & 7;
    float* A = abuf + ((size_t)bm * F + h * 32) * W;   // (B,M,F,W) rows h*32+d

    {   // stage Q block transposed
        int r = t & 63, dq = (t >> 6) * 8;
        float4 a  = *(const float4*)&Q[(size_t)(w0 + r) * HD + dq];
        float4 a2 = *(const float4*)&Q[(size_t)(w0 + r) * HD + dq + 4];
        QsT[dq + 0][r] = a.x;  QsT[dq + 1][r] = a.y;  QsT[dq + 2][r] = a.z;  QsT[dq + 3][r] = a.w;
        QsT[dq + 4][r] = a2.x; QsT[dq + 5][r] = a2.y; QsT[dq + 6][r] = a2.z; QsT[dq + 7][r] = a2.w;
    }
    int ty = t >> 4, tx = t & 15;   // rows ty*4.., cols tx*4..
    int ty4 = ty * 4;
    int dA = tx * 2;                // PV: this thread owns d = dA, dA+1
    float m_i[4], l_i[4], acc[4][2];
    #pragma unroll
    for (int i = 0; i < 4; ++i) { m_i[i] = -3.0e38f; l_i[i] = 0.f; acc[i][0] = 0.f; acc[i][1] = 0.f; }

    for (int c = 0; c < 8; ++c) {
        __syncthreads();   // protect LDS from previous chunk's consumers
        int j0 = c * 64;
        {   // stage K chunk transposed
            int r = t & 63, dq = (t >> 6) * 8;
            float4 a  = *(const float4*)&K[(size_t)(j0 + r) * HD + dq];
            float4 a2 = *(const float4*)&K[(size_t)(j0 + r) * HD + dq + 4];
            KsT[dq + 0][r] = a.x;  KsT[dq + 1][r] = a.y;  KsT[dq + 2][r] = a.z;  KsT[dq + 3][r] = a.w;
            KsT[dq + 4][r] = a2.x; KsT[dq + 5][r] = a2.y; KsT[dq + 6][r] = a2.z; KsT[dq + 7][r] = a2.w;
            // stage V chunk row-major
            int r2 = t >> 2, dq2 = (t & 3) * 8;
            float4 va  = *(const float4*)&V[(size_t)(j0 + r2) * HD + dq2];
            float4 va2 = *(const float4*)&V[(size_t)(j0 + r2) * HD + dq2 + 4];
            *(float4*)&Vs[r2][dq2] = va;
            *(float4*)&Vs[r2][dq2 + 4] = va2;
        }
        __syncthreads();
        // ---- scores: 4x4 tile over (rows ty4.., cols tx*4..), K=32 ----
        float s[4][4] = {};
        #pragma unroll
        for (int kk = 0; kk < 32; ++kk) {
            float4 a4 = *(const float4*)&QsT[kk][ty4];
            float4 b4 = *(const float4*)&KsT[kk][tx * 4];
            s[0][0] += a4.x * b4.x; s[0][1] += a4.x * b4.y; s[0][2] += a4.x * b4.z; s[0][3] += a4.x * b4.w;
            s[1][0] += a4.y * b4.x; s[1][1] += a4.y * b4.y; s[1][2] += a4.y * b4.z; s[1][3] += a4.y * b4.w;
            s[2][0] += a4.z * b4.x; s[2][1] += a4.z * b4.y; s[2][2] += a4.z * b4.z; s[2][3] += a4.z * b4.w;
            s[3][0] += a4.w * b4.x; s[3][1] += a4.w * b4.y; s[3][2] += a4.w * b4.z; s[3][3] += a4.w * b4.w;
        }
        // ---- scale + prev, write qk ----
        #pragma unroll
        for (int i = 0; i < 4; ++i) {
            size_t row = (size_t)(w0 + ty4 + i) * W + j0 + tx * 4;
            float4 pv = *(const float4*)&P0[row];
            s[i][0] = s[i][0] * 0.0625f + pv.x;
            s[i][1] = s[i][1] * 0.0625f + pv.y;
            s[i][2] = s[i][2] * 0.0625f + pv.z;
            s[i][3] = s[i][3] * 0.0625f + pv.w;
            *(float4*)&QK[row] = make_float4(s[i][0], s[i][1], s[i][2], s[i][3]);
        }
        // ---- online softmax update (row reduce across the 16 tx lanes) ----
        #pragma unroll
        for (int i = 0; i < 4; ++i) {
            float cm = fmaxf(fmaxf(s[i][0], s[i][1]), fmaxf(s[i][2], s[i][3]));
            #pragma unroll
            for (int off = 1; off < 16; off <<= 1) cm = fmaxf(cm, __shfl_xor(cm, off));
            float mn = fmaxf(m_i[i], cm);
            float alpha = __expf(m_i[i] - mn);
            m_i[i] = mn;
            float rs = 0.f;
            #pragma unroll
            for (int j = 0; j < 4; ++j) { s[i][j] = __expf(s[i][j] - mn); rs += s[i][j]; }
            #pragma unroll
            for (int off = 1; off < 16; off <<= 1) rs += __shfl_xor(rs, off);
            l_i[i] = l_i[i] * alpha + rs;
            acc[i][0] *= alpha; acc[i][1] *= alpha;
        }
        // ---- stage P transposed for PV ----
        #pragma unroll
        for (int i = 0; i < 4; ++i)
            #pragma unroll
            for (int j = 0; j < 4; ++j)
                PsT[tx * 4 + j][ty4 + i] = s[i][j];
        __syncthreads();
        // ---- PV: acc[i][dd] += sum_j P[row_i][j] * V[j][dA+dd] ----
        #pragma unroll 4
        for (int j = 0; j < 64; ++j) {
            float4 a4 = *(const float4*)&PsT[j][ty4];
            float2 b2 = *(const float2*)&Vs[j][dA];
            acc[0][0] += a4.x * b2.x; acc[0][1] += a4.x * b2.y;
            acc[1][0] += a4.y * b2.x; acc[1][1] += a4.y * b2.y;
            acc[2][0] += a4.z * b2.x; acc[2][1] += a4.z * b2.y;
            acc[3][0] += a4.w * b2.x; acc[3][1] += a4.w * b2.y;
        }
    }
    // ---- epilogue: normalize, transpose-stage, coalesced write of A ----
    __syncthreads();
    float* Ot = &PsT[0][0];     // reuse as [32][68]
    #pragma unroll
    for (int i = 0; i < 4; ++i) {
        float inv = 1.f / l_i[i];
        Ot[(dA + 0) * 68 + ty4 + i] = acc[i][0] * inv;
        Ot[(dA + 1) * 68 + ty4 + i] = acc[i][1] * inv;
    }
    __syncthreads();
    for (int k = 0; k < 8; ++k) {
        int idx = k * 256 + t;
        int d = idx >> 6, wi = idx & 63;
        A[(size_t)d * W + w0 + wi] = Ot[d * 68 + wi];
    }
}

// ---------------------------------------------------------------------------
extern "C" void kernel_launch(void* const* d_in, const int* in_sizes, int n_in,
                              void* d_out, int out_size, void* d_ws, size_t ws_size,
                              hipStream_t stream) {
    const float* x    = (const float*)d_in[0];
    const float* prev = (const float*)d_in[1];
    const float* qc1  = (const float*)d_in[2];
    const float* qlin = (const float*)d_in[3];
    const float* qc2  = (const float*)d_in[4];
    const float* kc1  = (const float*)d_in[5];
    const float* klin = (const float*)d_in[6];
    const float* kc2  = (const float*)d_in[7];
    const float* vc1  = (const float*)d_in[8];
    const float* vlin = (const float*)d_in[9];
    const float* vc2  = (const float*)d_in[10];
    const float* ow   = (const float*)d_in[11];
    float* out0  = (float*)d_out;
    float* qkout = out0 + (size_t)B * M * F * W;    // outputs: (out, qk) flat
    float* ws = (float*)d_ws;
    size_t n = (size_t)B * M * F * W;               // 2,097,152
    float* h1   = ws;
    float* h2   = ws + n;
    float* qbuf = ws + 2 * n;
    float* kbuf = ws + 3 * n;
    float* vbuf = ws + 4 * n;

    dim3 blk(256);
    dim3 gconv1(2, 256, 16), glin(8, 4, 16), gconv2(8, 4, 16), gattn(8, 128);

    // q projection
    conv1_kernel<<<gconv1, blk, 0, stream>>>(x, qc1, h1);
    lin_kernel<<<glin, blk, 0, stream>>>(h1, qlin, h2);
    conv2_heads_kernel<<<gconv2, blk, 0, stream>>>(h2, qc2, qbuf, 1);
    // k projection
    conv1_kernel<<<gconv1, blk, 0, stream>>>(x, kc1, h1);
    lin_kernel<<<glin, blk, 0, stream>>>(h1, klin, h2);
    conv2_heads_kernel<<<gconv2, blk, 0, stream>>>(h2, kc2, kbuf, 1);
    // v projection
    conv1_kernel<<<gconv1, blk, 0, stream>>>(x, vc1, h1);
    lin_kernel<<<glin, blk, 0, stream>>>(h1, vlin, h2);
    conv2_heads_kernel<<<gconv2, blk, 0, stream>>>(h2, vc2, vbuf, 0);
    // fused attention (writes qk output + A into h1)
    attn_kernel<<<gattn, blk, 0, stream>>>(qbuf, kbuf, vbuf, prev, qkout, h1);
    // output projection
    lin_kernel<<<glin, blk, 0, stream>>>(h1, ow, out0);
}

// Round 2
// 473.760 us; speedup vs baseline: 1.1590x; 1.1590x over previous
//
#include <hip/hip_runtime.h>

#define B 2
#define C 8
#define M 8
#define H 8
#define F 256
#define W 512
#define HD 32

// ---------------------------------------------------------------------------
// conv1: 3x3, C=8 -> M=8, pad (1,1). Batched over 3 projections via blockIdx.z.
// ---------------------------------------------------------------------------
__global__ __launch_bounds__(256) void conv1_kernel(const float* __restrict__ x,
                                                    const float* __restrict__ w0,
                                                    const float* __restrict__ w1,
                                                    const float* __restrict__ w2,
                                                    float* __restrict__ out) {
    __shared__ float wl[72];
    int t = threadIdx.x;
    int z = blockIdx.z;           // proj*16 + b*8 + m
    int proj = z >> 4, bz = z & 15;
    int b = bz >> 3, m = bz & 7;
    const float* wt = (proj == 0) ? w0 : (proj == 1) ? w1 : w2;
    if (t < 72) wl[t] = wt[m * 72 + t];
    __syncthreads();
    int f = blockIdx.y;
    int w = blockIdx.x * 256 + t;
    const float* xb = x + (size_t)b * C * F * W;
    float acc = 0.f;
    for (int i = 0; i < 8; ++i) {
        const float* xi = xb + (size_t)i * F * W;
        #pragma unroll
        for (int df = 0; df < 3; ++df) {
            int ff = f + df - 1;
            if (ff < 0 || ff >= F) continue;           // wave-uniform (f uniform per block)
            const float* xr = xi + (size_t)ff * W;
            float v0 = (w - 1 >= 0) ? xr[w - 1] : 0.f;
            float v1 = xr[w];
            float v2 = (w + 1 < W) ? xr[w + 1] : 0.f;
            const float* wr = &wl[(i * 3 + df) * 3];
            acc += v0 * wr[0] + v1 * wr[1] + v2 * wr[2];
        }
    }
    out[((size_t)z * F + f) * W + w] = acc;
}

// ---------------------------------------------------------------------------
// lin: per (proj,b,m): out[g][w] = sum_f wt[m][g][f] * in[z][f][w]
// 64x64 tile, BK=32, 4x4 micro-tile, register double-buffered staging.
// Batched over projections via blockIdx.z (out-proj call: z<16, all w ptrs = ow).
// ---------------------------------------------------------------------------
__global__ __launch_bounds__(256) void lin_kernel(const float* __restrict__ in,
                                                  const float* __restrict__ w0,
                                                  const float* __restrict__ w1,
                                                  const float* __restrict__ w2,
                                                  float* __restrict__ out) {
    __shared__ float As[32][68];   // As[kk][gg] = wt[g0+gg][f0+kk]
    __shared__ float Bs[32][68];   // Bs[kk][ww] = in[f0+kk][w0+ww]
    int t = threadIdx.x;
    int z = blockIdx.z;
    int proj = z >> 4, m = z & 7;
    const float* wsel = (proj == 0) ? w0 : (proj == 1) ? w1 : w2;
    const float* wm = wsel + (size_t)m * F * F;
    const float* ib = in + (size_t)z * F * W;
    float* ob = out + (size_t)z * F * W;
    int g0 = blockIdx.y * 64, wb0 = blockIdx.x * 64;
    int ty = t >> 4, tx = t & 15;
    int gg = t >> 2, fq = (t & 3) * 8;       // A staging: row gg, 8 consecutive f
    int lkk = t >> 3, wq = (t & 7) * 8;      // B staging: row lkk, 8 consecutive w
    float4 a0 = *(const float4*)&wm[(size_t)(g0 + gg) * F + fq];
    float4 a1 = *(const float4*)&wm[(size_t)(g0 + gg) * F + fq + 4];
    float4 b0 = *(const float4*)&ib[(size_t)lkk * W + wb0 + wq];
    float4 b1 = *(const float4*)&ib[(size_t)lkk * W + wb0 + wq + 4];
    float acc[4][4] = {};
    for (int f0 = 0; f0 < F; f0 += 32) {
        As[fq + 0][gg] = a0.x; As[fq + 1][gg] = a0.y; As[fq + 2][gg] = a0.z; As[fq + 3][gg] = a0.w;
        As[fq + 4][gg] = a1.x; As[fq + 5][gg] = a1.y; As[fq + 6][gg] = a1.z; As[fq + 7][gg] = a1.w;
        *(float4*)&Bs[lkk][wq] = b0;
        *(float4*)&Bs[lkk][wq + 4] = b1;
        __syncthreads();
        if (f0 + 32 < F) {   // prefetch next K-tile while computing this one
            a0 = *(const float4*)&wm[(size_t)(g0 + gg) * F + f0 + 32 + fq];
            a1 = *(const float4*)&wm[(size_t)(g0 + gg) * F + f0 + 32 + fq + 4];
            b0 = *(const float4*)&ib[(size_t)(f0 + 32 + lkk) * W + wb0 + wq];
            b1 = *(const float4*)&ib[(size_t)(f0 + 32 + lkk) * W + wb0 + wq + 4];
        }
        #pragma unroll
        for (int kk = 0; kk < 32; ++kk) {
            float4 a4 = *(const float4*)&As[kk][ty * 4];
            float4 b4 = *(const float4*)&Bs[kk][tx * 4];
            acc[0][0] += a4.x * b4.x; acc[0][1] += a4.x * b4.y; acc[0][2] += a4.x * b4.z; acc[0][3] += a4.x * b4.w;
            acc[1][0] += a4.y * b4.x; acc[1][1] += a4.y * b4.y; acc[1][2] += a4.y * b4.z; acc[1][3] += a4.y * b4.w;
            acc[2][0] += a4.z * b4.x; acc[2][1] += a4.z * b4.y; acc[2][2] += a4.z * b4.z; acc[2][3] += a4.z * b4.w;
            acc[3][0] += a4.w * b4.x; acc[3][1] += a4.w * b4.y; acc[3][2] += a4.w * b4.z; acc[3][3] += a4.w * b4.w;
        }
        __syncthreads();
    }
    #pragma unroll
    for (int i = 0; i < 4; ++i) {
        float4 o = make_float4(acc[i][0], acc[i][1], acc[i][2], acc[i][3]);
        *(float4*)&ob[(size_t)(g0 + ty * 4 + i) * W + wb0 + tx * 4] = o;
    }
}

// ---------------------------------------------------------------------------
// conv2 (1x3, M-mix) + heads transpose + rotary (projections 0,1 only).
// Batched over projections via blockIdx.z.
// ---------------------------------------------------------------------------
__global__ __launch_bounds__(256) void conv2_heads_kernel(const float* __restrict__ in,
                                                          const float* __restrict__ w0c,
                                                          const float* __restrict__ w1c,
                                                          const float* __restrict__ w2c,
                                                          float* __restrict__ outp) {
    __shared__ float wl[192];           // wc2[o][i][dw]
    __shared__ float Ot[64][65];        // [f-offset][w-offset]
    int t = threadIdx.x;
    int z = blockIdx.z;                 // proj*16 + b*8 + o
    int proj = z >> 4, bz = z & 15;
    int b = bz >> 3, o = bz & 7;
    const float* wt = (proj == 0) ? w0c : (proj == 1) ? w1c : w2c;
    int do_rot = (proj < 2);
    if (t < 192) wl[t] = wt[t];
    __syncthreads();
    int f0 = blockIdx.y * 64, w0 = blockIdx.x * 64;
    const float* ib = in + ((size_t)proj * 16 + (size_t)b * M) * F * W;
    int ww = t & 63, fq = (t >> 6) * 16;
    int w = w0 + ww;
    for (int ff = 0; ff < 16; ++ff) {
        int f = f0 + fq + ff;
        float acc = 0.f;
        #pragma unroll
        for (int i = 0; i < 8; ++i) {
            const float* r = ib + ((size_t)i * F + f) * W + w;
            float v0 = (w - 1 >= 0) ? r[-1] : 0.f;
            float v1 = r[0];
            float v2 = (w + 1 < W) ? r[1] : 0.f;
            const float* wr = &wl[(o * 8 + i) * 3];
            acc += v0 * wr[0] + v1 * wr[1] + v2 * wr[2];
        }
        Ot[fq + ff][ww] = acc;
    }
    __syncthreads();
    // write phase: lanes run over f-offset (=> d contiguous), iterate w
    for (int k = 0; k < 16; ++k) {
        int idx = k * 256 + t;
        int ddh = idx & 63;      // f offset in tile
        int wi = idx >> 6;       // w offset in tile
        int f = f0 + ddh;
        int h = f >> 5, d = f & 31;
        float val;
        if (do_rot) {
            float e  = Ot[ddh & ~1][wi];
            float od = Ot[ddh | 1][wi];
            int jp = d >> 1;
            float invf = exp2f(-(float)jp * 0.83048202372184058f);  // 10000^(-jp/16)
            float th = (float)(w0 + wi) * invf;
            float cs = __cosf(th), sn = __sinf(th);
            val = (d & 1) ? (od * cs + e * sn) : (e * cs - od * sn);
        } else {
            val = Ot[ddh][wi];
        }
        outp[(((size_t)z * H + h) * W + (w0 + wi)) * HD + d] = val;
    }
}

// ---------------------------------------------------------------------------
// Fused attention: per (bmh, 64-row block): loop 8 chunks of 64 cols.
// LDS: KsT aliased with PsT (KP) -> 35.3 KB -> 4 blocks/CU (one clean pass of
// the 1024-block grid). K/V chunk c+1 and prev rows are register-prefetched
// before the score loop so global latency overlaps compute.
// ---------------------------------------------------------------------------
__global__ __launch_bounds__(256) void attn_kernel(const float* __restrict__ qb,
                                                   const float* __restrict__ kb,
                                                   const float* __restrict__ vb,
                                                   const float* __restrict__ prev,
                                                   float* __restrict__ qk,
                                                   float* __restrict__ abuf) {
    __shared__ float QsT[32][68];   // [d][row]          8704 B
    __shared__ float Vs[64][36];    // [col][d]          9216 B
    __shared__ float KP[64][68];    // rows 0..31: KsT[d][col]; full: PsT[col][row]; epilogue: Ot
    int t = threadIdx.x;
    int w0 = blockIdx.x * 64;       // q-row block
    int bmh = blockIdx.y;           // 0..127
    const float* Q = qb + (size_t)bmh * W * HD;
    const float* K = kb + (size_t)bmh * W * HD;
    const float* V = vb + (size_t)bmh * W * HD;
    const float* P0 = prev + (size_t)bmh * W * W;
    float* QK = qk + (size_t)bmh * W * W;
    int bm = bmh >> 3, h = bmh & 7;
    float* A = abuf + ((size_t)bm * F + h * 32) * W;   // (B,M,F,W) rows h*32+d

    int r = t & 63, dq = (t >> 6) * 8;      // K/Q staging lanes
    int rv = t >> 2, dv = (t & 3) * 8;      // V staging lanes
    {   // stage Q block transposed
        float4 a  = *(const float4*)&Q[(size_t)(w0 + r) * HD + dq];
        float4 a2 = *(const float4*)&Q[(size_t)(w0 + r) * HD + dq + 4];
        QsT[dq + 0][r] = a.x;  QsT[dq + 1][r] = a.y;  QsT[dq + 2][r] = a.z;  QsT[dq + 3][r] = a.w;
        QsT[dq + 4][r] = a2.x; QsT[dq + 5][r] = a2.y; QsT[dq + 6][r] = a2.z; QsT[dq + 7][r] = a2.w;
    }
    // prefetch + stage chunk 0 K/V
    float4 ka  = *(const float4*)&K[(size_t)r * HD + dq];
    float4 ka2 = *(const float4*)&K[(size_t)r * HD + dq + 4];
    float4 va  = *(const float4*)&V[(size_t)rv * HD + dv];
    float4 va2 = *(const float4*)&V[(size_t)rv * HD + dv + 4];
    KP[dq + 0][r] = ka.x;  KP[dq + 1][r] = ka.y;  KP[dq + 2][r] = ka.z;  KP[dq + 3][r] = ka.w;
    KP[dq + 4][r] = ka2.x; KP[dq + 5][r] = ka2.y; KP[dq + 6][r] = ka2.z; KP[dq + 7][r] = ka2.w;
    *(float4*)&Vs[rv][dv] = va;
    *(float4*)&Vs[rv][dv + 4] = va2;

    int ty = t >> 4, tx = t & 15;
    int ty4 = ty * 4;
    int dA = tx * 2;                // PV: this thread owns d = dA, dA+1
    float m_i[4], l_i[4], acc[4][2];
    #pragma unroll
    for (int i = 0; i < 4; ++i) { m_i[i] = -3.0e38f; l_i[i] = 0.f; acc[i][0] = 0.f; acc[i][1] = 0.f; }

    for (int c = 0; c < 8; ++c) {
        __syncthreads();             // (D) staged K_c/V_c visible
        int j0 = c * 64;
        if (c < 7) {                 // prefetch next chunk into registers
            ka  = *(const float4*)&K[(size_t)(j0 + 64 + r) * HD + dq];
            ka2 = *(const float4*)&K[(size_t)(j0 + 64 + r) * HD + dq + 4];
            va  = *(const float4*)&V[(size_t)(j0 + 64 + rv) * HD + dv];
            va2 = *(const float4*)&V[(size_t)(j0 + 64 + rv) * HD + dv + 4];
        }
        float4 pv[4];                // prefetch prev rows
        #pragma unroll
        for (int i = 0; i < 4; ++i)
            pv[i] = *(const float4*)&P0[(size_t)(w0 + ty4 + i) * W + j0 + tx * 4];
        // ---- scores: 4x4 tile, K=32 ----
        float s[4][4] = {};
        #pragma unroll
        for (int kk = 0; kk < 32; ++kk) {
            float4 a4 = *(const float4*)&QsT[kk][ty4];
            float4 b4 = *(const float4*)&KP[kk][tx * 4];
            s[0][0] += a4.x * b4.x; s[0][1] += a4.x * b4.y; s[0][2] += a4.x * b4.z; s[0][3] += a4.x * b4.w;
            s[1][0] += a4.y * b4.x; s[1][1] += a4.y * b4.y; s[1][2] += a4.y * b4.z; s[1][3] += a4.y * b4.w;
            s[2][0] += a4.z * b4.x; s[2][1] += a4.z * b4.y; s[2][2] += a4.z * b4.z; s[2][3] += a4.z * b4.w;
            s[3][0] += a4.w * b4.x; s[3][1] += a4.w * b4.y; s[3][2] += a4.w * b4.z; s[3][3] += a4.w * b4.w;
        }
        __syncthreads();             // (A) KsT region free
        // ---- scale + prev, write qk ----
        #pragma unroll
        for (int i = 0; i < 4; ++i) {
            size_t row = (size_t)(w0 + ty4 + i) * W + j0 + tx * 4;
            s[i][0] = s[i][0] * 0.0625f + pv[i].x;
            s[i][1] = s[i][1] * 0.0625f + pv[i].y;
            s[i][2] = s[i][2] * 0.0625f + pv[i].z;
            s[i][3] = s[i][3] * 0.0625f + pv[i].w;
            *(float4*)&QK[row] = make_float4(s[i][0], s[i][1], s[i][2], s[i][3]);
        }
        // ---- online softmax update (row reduce across the 16 tx lanes) ----
        #pragma unroll
        for (int i = 0; i < 4; ++i) {
            float cm = fmaxf(fmaxf(s[i][0], s[i][1]), fmaxf(s[i][2], s[i][3]));
            #pragma unroll
            for (int off = 1; off < 16; off <<= 1) cm = fmaxf(cm, __shfl_xor(cm, off));
            float mn = fmaxf(m_i[i], cm);
            float alpha = __expf(m_i[i] - mn);
            m_i[i] = mn;
            float rs = 0.f;
            #pragma unroll
            for (int j = 0; j < 4; ++j) { s[i][j] = __expf(s[i][j] - mn); rs += s[i][j]; }
            #pragma unroll
            for (int off = 1; off < 16; off <<= 1) rs += __shfl_xor(rs, off);
            l_i[i] = l_i[i] * alpha + rs;
            acc[i][0] *= alpha; acc[i][1] *= alpha;
        }
        // ---- stage P transposed (over the KsT region) ----
        #pragma unroll
        for (int i = 0; i < 4; ++i)
            #pragma unroll
            for (int j = 0; j < 4; ++j)
                KP[tx * 4 + j][ty4 + i] = s[i][j];
        __syncthreads();             // (B) PsT visible
        // ---- PV: acc[i][dd] += sum_j P[row_i][j] * V[j][dA+dd] ----
        #pragma unroll 4
        for (int j = 0; j < 64; ++j) {
            float4 a4 = *(const float4*)&KP[j][ty4];
            float2 b2 = *(const float2*)&Vs[j][dA];
            acc[0][0] += a4.x * b2.x; acc[0][1] += a4.x * b2.y;
            acc[1][0] += a4.y * b2.x; acc[1][1] += a4.y * b2.y;
            acc[2][0] += a4.z * b2.x; acc[2][1] += a4.z * b2.y;
            acc[3][0] += a4.w * b2.x; acc[3][1] += a4.w * b2.y;
        }
        __syncthreads();             // (C) PsT / Vs free
        if (c < 7) {                 // stage next chunk from registers
            KP[dq + 0][r] = ka.x;  KP[dq + 1][r] = ka.y;  KP[dq + 2][r] = ka.z;  KP[dq + 3][r] = ka.w;
            KP[dq + 4][r] = ka2.x; KP[dq + 5][r] = ka2.y; KP[dq + 6][r] = ka2.z; KP[dq + 7][r] = ka2.w;
            *(float4*)&Vs[rv][dv] = va;
            *(float4*)&Vs[rv][dv + 4] = va2;
        }
    }
    // ---- epilogue: normalize, transpose-stage, coalesced write of A ----
    float* Ot = &KP[0][0];     // reuse as [32][68]; safe after barrier (C)
    #pragma unroll
    for (int i = 0; i < 4; ++i) {
        float inv = 1.f / l_i[i];
        Ot[(dA + 0) * 68 + ty4 + i] = acc[i][0] * inv;
        Ot[(dA + 1) * 68 + ty4 + i] = acc[i][1] * inv;
    }
    __syncthreads();
    for (int k = 0; k < 8; ++k) {
        int idx = k * 256 + t;
        int d = idx >> 6, wi = idx & 63;
        A[(size_t)d * W + w0 + wi] = Ot[d * 68 + wi];
    }
}

// ---------------------------------------------------------------------------
extern "C" void kernel_launch(void* const* d_in, const int* in_sizes, int n_in,
                              void* d_out, int out_size, void* d_ws, size_t ws_size,
                              hipStream_t stream) {
    const float* x    = (const float*)d_in[0];
    const float* prev = (const float*)d_in[1];
    const float* qc1  = (const float*)d_in[2];
    const float* qlin = (const float*)d_in[3];
    const float* qc2  = (const float*)d_in[4];
    const float* kc1  = (const float*)d_in[5];
    const float* klin = (const float*)d_in[6];
    const float* kc2  = (const float*)d_in[7];
    const float* vc1  = (const float*)d_in[8];
    const float* vlin = (const float*)d_in[9];
    const float* vc2  = (const float*)d_in[10];
    const float* ow   = (const float*)d_in[11];
    float* out0  = (float*)d_out;
    float* qkout = out0 + (size_t)B * M * F * W;    // outputs: (out, qk) flat
    float* ws = (float*)d_ws;
    size_t n = (size_t)B * M * F * W;               // 2,097,152
    // ws layout: [0,3n) = conv1 outs (q,k,v), then reused as conv2 outs (q,k,v)
    //            [3n,6n) = lin outs (q,k,v), then reused as attention A
    float* r1 = ws;          // conv1 outs / qkv bufs
    float* r2 = ws + 3 * n;  // lin outs / A

    dim3 blk(256);
    dim3 gconv1(2, 256, 48), glin3(8, 4, 48), gconv2(8, 4, 48);
    dim3 gattn(8, 128), glin1(8, 4, 16);

    conv1_kernel<<<gconv1, blk, 0, stream>>>(x, qc1, kc1, vc1, r1);
    lin_kernel<<<glin3, blk, 0, stream>>>(r1, qlin, klin, vlin, r2);
    conv2_heads_kernel<<<gconv2, blk, 0, stream>>>(r2, qc2, kc2, vc2, r1);
    attn_kernel<<<gattn, blk, 0, stream>>>(r1, r1 + n, r1 + 2 * n, prev, qkout, r2);
    lin_kernel<<<glin1, blk, 0, stream>>>(r2, ow, ow, ow, out0);
}